// Round 6
// baseline (122.427 us; speedup 1.0000x reference)
//
#include <hip/hip_runtime.h>
#include <math.h>

namespace {

constexpr int Bsz   = 16384;
constexpr int T     = 200;
constexpr int F     = 4;
constexpr int H     = 10;
constexpr int HP    = 16;   // hidden padded: 8 lanes x 2 units
constexpr int BLOCK = 256;

// tanh(x) = 1 - 2/(exp(2x)+1); saturates correctly to +/-1 for |x| large.
__device__ __forceinline__ float fast_tanh(float x) {
  float e = exp2f(x * 2.8853900817779268f);   // exp(2x) via v_exp_f32
  return 1.0f - 2.0f * __builtin_amdgcn_rcpf(e + 1.0f);
}

__device__ __forceinline__ float fast_sigmoid(float x) {
  float e = exp2f(x * -1.4426950408889634f);  // exp(-x)
  return __builtin_amdgcn_rcpf(1.0f + e);
}

// quad_perm broadcast: every lane gets ITS OWN quad's lane-J value. VALU rate.
template <int J>
__device__ __forceinline__ float qb(float v) {
  return __int_as_float(__builtin_amdgcn_mov_dpp(
      __float_as_int(v), J * 0x55, 0xF, 0xF, true));
}

// row_half_mirror (0x141): lane i <-> lane 7-i within each 8-lane half-row.
// Always crosses the quad boundary inside an 8-group -> fetches the OTHER
// quad's (quad-uniform) value. VALU rate, no LDS pipe.
__device__ __forceinline__ float mir8(float v) {
  return __int_as_float(__builtin_amdgcn_mov_dpp(
      __float_as_int(v), 0x141, 0xF, 0xF, true));
}

// Prevent rematerialization of a loaded value inside the t-loop.
#define PIN(v) asm volatile("" : "+v"(v))

// waves_per_eu(2,2): pin the compiler's occupancy TARGET to exactly 2
// waves/SIMD -> register-pressure budget 256 VGPR. Without the max bound the
// scheduler aims for default-high occupancy and SPILLS the pinned weights to
// scratch (rounds 2-5: VGPR_Count 52-80 despite 100+ live values; per-step
// scratch reloads were the hidden stall).
__global__ __launch_bounds__(BLOCK)
__attribute__((amdgpu_waves_per_eu(2, 2)))
void rnn2_oct_dpp(
    const float* __restrict__ x,
    const float* __restrict__ W_ih0, const float* __restrict__ W_hh0,
    const float* __restrict__ b_ih0, const float* __restrict__ b_hh0,
    const float* __restrict__ W_ih1, const float* __restrict__ W_hh1,
    const float* __restrict__ b_ih1, const float* __restrict__ b_hh1,
    const float* __restrict__ W_fc, const float* __restrict__ b_fc,
    float* __restrict__ out) {
  // FC weights in LDS, padded to HP floats per timestep (pad = 0).
  __shared__ float s_wfc[T * HP];
  for (int i = threadIdx.x; i < T * HP; i += BLOCK) {
    int t = i >> 4, u = i & 15;
    s_wfc[i] = (u < H) ? W_fc[t * H + u] : 0.0f;
  }
  __syncthreads();

  const int g  = blockIdx.x * BLOCK + threadIdx.x;
  const int b  = g >> 3;                    // batch element
  const int r  = g & 7;                     // sub-lane in 8-group
  const int qp = (threadIdx.x >> 2) & 1;    // quad parity within the 8-group
  const int uA = r;                         // first unit (real: r<=7<10)
  const int uB = 8 + r;                     // second unit (real only r<2)
  const bool vB = (uB < H);

  // ---- weights, permuted "own-quad-first" so the DPP exchange needs no
  //      cndmask: own[j] pairs with quad_perm<j>, oth[j] with its mirror. ----
  float wi0A[F], wi0B[F];
  float h0A_ow[4], h0A_ot[4], h0A_hi[2], h0B_ow[4], h0B_ot[4], h0B_hi[2];
  float i1A_ow[4], i1A_ot[4], i1A_hi[2], i1B_ow[4], i1B_ot[4], i1B_hi[2];
  float h1A_ow[4], h1A_ot[4], h1A_hi[2], h1B_ow[4], h1B_ot[4], h1B_hi[2];
  float bA0, bB0, bA1, bB1;

#pragma unroll
  for (int j = 0; j < F; ++j) {
    wi0A[j] = W_ih0[uA * F + j];             PIN(wi0A[j]);
    wi0B[j] = vB ? W_ih0[uB * F + j] : 0.0f; PIN(wi0B[j]);
  }
#pragma unroll
  for (int j = 0; j < 4; ++j) {
    const int ou = qp ? 4 + j : j;   // own-quad unit index
    const int xu = qp ? j : 4 + j;   // other-quad unit index
    h0A_ow[j] = W_hh0[uA * H + ou];             PIN(h0A_ow[j]);
    h0A_ot[j] = W_hh0[uA * H + xu];             PIN(h0A_ot[j]);
    h0B_ow[j] = vB ? W_hh0[uB * H + ou] : 0.0f; PIN(h0B_ow[j]);
    h0B_ot[j] = vB ? W_hh0[uB * H + xu] : 0.0f; PIN(h0B_ot[j]);
    i1A_ow[j] = W_ih1[uA * H + ou];             PIN(i1A_ow[j]);
    i1A_ot[j] = W_ih1[uA * H + xu];             PIN(i1A_ot[j]);
    i1B_ow[j] = vB ? W_ih1[uB * H + ou] : 0.0f; PIN(i1B_ow[j]);
    i1B_ot[j] = vB ? W_ih1[uB * H + xu] : 0.0f; PIN(i1B_ot[j]);
    h1A_ow[j] = W_hh1[uA * H + ou];             PIN(h1A_ow[j]);
    h1A_ot[j] = W_hh1[uA * H + xu];             PIN(h1A_ot[j]);
    h1B_ow[j] = vB ? W_hh1[uB * H + ou] : 0.0f; PIN(h1B_ow[j]);
    h1B_ot[j] = vB ? W_hh1[uB * H + xu] : 0.0f; PIN(h1B_ot[j]);
  }
#pragma unroll
  for (int j = 0; j < 2; ++j) {
    h0A_hi[j] = W_hh0[uA * H + 8 + j];             PIN(h0A_hi[j]);
    h0B_hi[j] = vB ? W_hh0[uB * H + 8 + j] : 0.0f; PIN(h0B_hi[j]);
    i1A_hi[j] = W_ih1[uA * H + 8 + j];             PIN(i1A_hi[j]);
    i1B_hi[j] = vB ? W_ih1[uB * H + 8 + j] : 0.0f; PIN(i1B_hi[j]);
    h1A_hi[j] = W_hh1[uA * H + 8 + j];             PIN(h1A_hi[j]);
    h1B_hi[j] = vB ? W_hh1[uB * H + 8 + j] : 0.0f; PIN(h1B_hi[j]);
  }
  bA0 = b_ih0[uA] + b_hh0[uA];               PIN(bA0);
  bB0 = vB ? (b_ih0[uB] + b_hh0[uB]) : 0.0f; PIN(bB0);
  bA1 = b_ih1[uA] + b_hh1[uA];               PIN(bA1);
  bB1 = vB ? (b_ih1[uB] + b_hh1[uB]) : 0.0f; PIN(bB1);

  const float4* __restrict__ xrow =
      reinterpret_cast<const float4*>(x + (size_t)b * (T * F));

  // h-state, in the same own/oth/hi layout (values, broadcast to all lanes).
  float h0ow[4] = {0, 0, 0, 0}, h0ot[4] = {0, 0, 0, 0}, h0hi[2] = {0, 0};
  float h1ow[4] = {0, 0, 0, 0}, h1ot[4] = {0, 0, 0, 0}, h1hi[2] = {0, 0};
  float acc = 0.0f;

  float4 xv = xrow[0];
#pragma unroll 1
  for (int t = 0; t < T; ++t) {
    float4 xn = (t + 1 < T) ? xrow[t + 1] : xv;  // software prefetch

    // FC weights for this step (LDS broadcast, issued early).
    float fA = s_wfc[t * HP + uA];
    float fB = s_wfc[t * HP + uB];

    // ---- layer 0 ----
    float sA = bA0, sB = bB0;
    sA = fmaf(wi0A[0], xv.x, sA);  sB = fmaf(wi0B[0], xv.x, sB);
    sA = fmaf(wi0A[1], xv.y, sA);  sB = fmaf(wi0B[1], xv.y, sB);
    sA = fmaf(wi0A[2], xv.z, sA);  sB = fmaf(wi0B[2], xv.z, sB);
    sA = fmaf(wi0A[3], xv.w, sA);  sB = fmaf(wi0B[3], xv.w, sB);
#pragma unroll
    for (int j = 0; j < 4; ++j) {
      sA = fmaf(h0A_ow[j], h0ow[j], sA);
      sB = fmaf(h0B_ow[j], h0ow[j], sB);
      sA = fmaf(h0A_ot[j], h0ot[j], sA);
      sB = fmaf(h0B_ot[j], h0ot[j], sB);
    }
    sA = fmaf(h0A_hi[0], h0hi[0], sA); sA = fmaf(h0A_hi[1], h0hi[1], sA);
    sB = fmaf(h0B_hi[0], h0hi[0], sB); sB = fmaf(h0B_hi[1], h0hi[1], sB);

    float mA = fast_tanh(sA);
    float mB = fast_tanh(sB);   // pad lanes: tanh(0) = 0 exactly

    // exchange new h0 across the 8-group (pure DPP)
    h0ow[0] = qb<0>(mA); h0ot[0] = mir8(h0ow[0]);
    h0ow[1] = qb<1>(mA); h0ot[1] = mir8(h0ow[1]);
    h0ow[2] = qb<2>(mA); h0ot[2] = mir8(h0ow[2]);
    h0ow[3] = qb<3>(mA); h0ot[3] = mir8(h0ow[3]);
    { float u8 = qb<0>(mB); h0hi[0] = u8 + mir8(u8);   // other quad's copy = 0
      float u9 = qb<1>(mB); h0hi[1] = u9 + mir8(u9); }

    // ---- layer 1 ----
    sA = bA1; sB = bB1;
#pragma unroll
    for (int j = 0; j < 4; ++j) {
      sA = fmaf(i1A_ow[j], h0ow[j], sA);
      sB = fmaf(i1B_ow[j], h0ow[j], sB);
      sA = fmaf(i1A_ot[j], h0ot[j], sA);
      sB = fmaf(i1B_ot[j], h0ot[j], sB);
    }
    sA = fmaf(i1A_hi[0], h0hi[0], sA); sA = fmaf(i1A_hi[1], h0hi[1], sA);
    sB = fmaf(i1B_hi[0], h0hi[0], sB); sB = fmaf(i1B_hi[1], h0hi[1], sB);
#pragma unroll
    for (int j = 0; j < 4; ++j) {
      sA = fmaf(h1A_ow[j], h1ow[j], sA);
      sB = fmaf(h1B_ow[j], h1ow[j], sB);
      sA = fmaf(h1A_ot[j], h1ot[j], sA);
      sB = fmaf(h1B_ot[j], h1ot[j], sB);
    }
    sA = fmaf(h1A_hi[0], h1hi[0], sA); sA = fmaf(h1A_hi[1], h1hi[1], sA);
    sB = fmaf(h1B_hi[0], h1hi[0], sB); sB = fmaf(h1B_hi[1], h1hi[1], sB);

    mA = fast_tanh(sA);
    mB = fast_tanh(sB);

    // FC head contribution (pad units read 0 weights from LDS)
    acc = fmaf(mA, fA, acc);
    acc = fmaf(mB, fB, acc);

    // exchange new h1
    h1ow[0] = qb<0>(mA); h1ot[0] = mir8(h1ow[0]);
    h1ow[1] = qb<1>(mA); h1ot[1] = mir8(h1ow[1]);
    h1ow[2] = qb<2>(mA); h1ot[2] = mir8(h1ow[2]);
    h1ow[3] = qb<3>(mA); h1ot[3] = mir8(h1ow[3]);
    { float u8 = qb<0>(mB); h1hi[0] = u8 + mir8(u8);
      float u9 = qb<1>(mB); h1hi[1] = u9 + mir8(u9); }

    xv = xn;
  }

  // 8-lane reduce of the FC accumulator
  acc += __shfl_xor(acc, 1);
  acc += __shfl_xor(acc, 2);
  acc += __shfl_xor(acc, 4);
  if (r == 0) out[b] = fast_sigmoid(acc + b_fc[0]);
}

}  // namespace

extern "C" void kernel_launch(void* const* d_in, const int* in_sizes, int n_in,
                              void* d_out, int out_size, void* d_ws, size_t ws_size,
                              hipStream_t stream) {
  const float* x     = (const float*)d_in[0];
  const float* W_ih0 = (const float*)d_in[1];
  const float* W_hh0 = (const float*)d_in[2];
  const float* b_ih0 = (const float*)d_in[3];
  const float* b_hh0 = (const float*)d_in[4];
  const float* W_ih1 = (const float*)d_in[5];
  const float* W_hh1 = (const float*)d_in[6];
  const float* b_ih1 = (const float*)d_in[7];
  const float* b_hh1 = (const float*)d_in[8];
  const float* W_fc  = (const float*)d_in[9];
  const float* b_fc  = (const float*)d_in[10];
  float* out = (float*)d_out;

  dim3 grid((Bsz * 8) / BLOCK), block(BLOCK);
  hipLaunchKernelGGL(rnn2_oct_dpp, grid, block, 0, stream,
                     x, W_ih0, W_hh0, b_ih0, b_hh0,
                     W_ih1, W_hh1, b_ih1, b_hh1, W_fc, b_fc, out);
}